// Round 5
// baseline (674.298 us; speedup 1.0000x reference)
//
#include <hip/hip_runtime.h>
#include <hip/hip_bf16.h>

#define Bb 64
#define Tt 20
#define Ee 512
#define Vv 32000
#define NB 32            // blocks in recurrent kernel

typedef __hip_bfloat16 bf16;
typedef __attribute__((ext_vector_type(8))) short bf16x8;
typedef __attribute__((ext_vector_type(4))) float f32x4;

__device__ __forceinline__ bf16 f2bf(float x) { return __float2bfloat16(x); }

// ---------------------------------------------------------------------------
// Kernel 0: fp32 -> bf16 weight conversion (W_ih / W_hh).
// ---------------------------------------------------------------------------
__global__ void convert_w(const float* __restrict__ src, bf16* __restrict__ dst) {
  int i = blockIdx.x * blockDim.x + threadIdx.x;
  float4 v = ((const float4*)src)[i];
  union { ushort4 u; bf16 h[4]; } pk;
  pk.h[0] = f2bf(v.x); pk.h[1] = f2bf(v.y); pk.h[2] = f2bf(v.z); pk.h[3] = f2bf(v.w);
  ((ushort4*)dst)[i] = pk.u;
}

// ---------------------------------------------------------------------------
// Kernel 1: embedding gather (fp32 -> bf16) + barrier-flag reset.
//  bar layout: arrive flags at bar[b*16] (64B stride, b<NB).
// ---------------------------------------------------------------------------
__global__ void embed_init(const int* __restrict__ caps, const float* __restrict__ Wemb,
                           bf16* __restrict__ emb, bf16* __restrict__ seq,
                           unsigned int* __restrict__ bar) {
  int row = blockIdx.x;            // b*T + t
  int t = row % Tt;
  int tid = threadIdx.x;           // 0..127
  if (row == 0) {
    for (int i = tid; i < NB * 16 + Tt; i += 128) bar[i] = 0;
  }
  int tok = caps[row];
  float4 v = ((const float4*)(Wemb + (size_t)tok * Ee))[tid];
  union { ushort4 u; bf16 h[4]; } pk;
  pk.h[0] = f2bf(v.x); pk.h[1] = f2bf(v.y); pk.h[2] = f2bf(v.z); pk.h[3] = f2bf(v.w);
  ((ushort4*)(emb + (size_t)row * Ee))[tid] = pk.u;
  if (t == 0) ((ushort4*)(seq + (size_t)row * Ee))[tid] = pk.u;   // row == b*T
}

// ---------------------------------------------------------------------------
// Kernel 2: x-projection (R0 GEMM skeleton, 32 KB LDS, multi-block/CU):
//   gx[row, col] = emb[row,:] @ W_ih[col,:] + bih[col] + bhh[col]
// grid = (16 n-tiles, 10 m-tiles), 256 threads, 128x128 tile, BK=64.
// ---------------------------------------------------------------------------
__global__ __launch_bounds__(256) void xproj(
    const bf16* __restrict__ A,     // emb [1280,512] bf16
    const bf16* __restrict__ Bw,    // W_ih [2048,512] bf16
    const float* __restrict__ bih, const float* __restrict__ bhh,
    float* __restrict__ gx)         // [1280,2048] fp32
{
  __shared__ __align__(16) bf16 As[128 * 64];   // 16 KB
  __shared__ __align__(16) bf16 Bs[128 * 64];   // 16 KB
  int tid = threadIdx.x;
  int lane = tid & 63;
  int quad = lane >> 4, ln = lane & 15;
  int wid = tid >> 6;
  int wm = wid & 1, wn = wid >> 1;
  int n0 = blockIdx.x * 128, m0 = blockIdx.y * 128;

  f32x4 zero = {0.f, 0.f, 0.f, 0.f};
  f32x4 acc[4][4];
#pragma unroll
  for (int mt = 0; mt < 4; ++mt)
#pragma unroll
    for (int nt = 0; nt < 4; ++nt) acc[mt][nt] = zero;

  for (int k0 = 0; k0 < Ee; k0 += 64) {
    uint4 avv[4], bvv[4];
#pragma unroll
    for (int q = 0; q < 4; ++q) {
      int fb = (q * 256 + tid) * 16;   // byte offset within bf16 tile
      int row = fb >> 7;               // 128 B per row (64 bf16)
      int cb = fb & 127;
      avv[q] = *(const uint4*)((const char*)A + ((size_t)(m0 + row) * Ee + k0) * 2 + cb);
      bvv[q] = *(const uint4*)((const char*)Bw + ((size_t)(n0 + row) * Ee + k0) * 2 + cb);
    }
#pragma unroll
    for (int q = 0; q < 4; ++q) {
      int fb = (q * 256 + tid) * 16;
      *(uint4*)((char*)As + fb) = avv[q];
      *(uint4*)((char*)Bs + fb) = bvv[q];
    }
    __syncthreads();

#pragma unroll
    for (int kk = 0; kk < 2; ++kk) {
      int kb = (kk * 32 + quad * 8) * 2;
      bf16x8 af[4], bfv[4];
#pragma unroll
      for (int mt = 0; mt < 4; ++mt)
        af[mt] = *(const bf16x8*)((const char*)As + (wm * 64 + mt * 16 + ln) * 128 + kb);
#pragma unroll
      for (int nt = 0; nt < 4; ++nt)
        bfv[nt] = *(const bf16x8*)((const char*)Bs + (wn * 64 + nt * 16 + ln) * 128 + kb);
#pragma unroll
      for (int mt = 0; mt < 4; ++mt)
#pragma unroll
        for (int nt = 0; nt < 4; ++nt)
          acc[mt][nt] = __builtin_amdgcn_mfma_f32_16x16x32_bf16(af[mt], bfv[nt], acc[mt][nt], 0, 0, 0);
    }
    __syncthreads();
  }

#pragma unroll
  for (int nt = 0; nt < 4; ++nt) {
    int col = n0 + wn * 64 + nt * 16 + ln;
    float bsum = bih[col] + bhh[col];
#pragma unroll
    for (int mt = 0; mt < 4; ++mt) {
#pragma unroll
      for (int r = 0; r < 4; ++r) {
        int row = m0 + wm * 64 + mt * 16 + quad * 4 + r;
        gx[(size_t)row * (4 * Ee) + col] = acc[mt][nt][r] + bsum;
      }
    }
  }
}

// ---------------------------------------------------------------------------
// Kernel 3: recurrent part, ALL 19 steps, one plain launch, 32 blocks x 256.
//  ZERO cache-maintenance design: the ONLY cross-block data (h) moves via
//  relaxed agent-scope atomics (sc0 sc1 -> write-through / read-from IC),
//  so the flag barrier needs no release/acquire/fence at all. gx & W_hh
//  stay L2-warm for the whole kernel (no invalidates ever happen).
//  - W_hh slice LDS-resident; gx+biases pre-folded; c in regs.
//  - gx for the NEXT step prefetched into registers (float4) pre-barrier.
//  - Barrier: syncthreads (drains h stores, vmcnt0) -> relaxed store of own
//    64B-strided flag (=t) -> lanes 0..31 poll all 32 flags (relaxed) ->
//    syncthreads.
// ---------------------------------------------------------------------------
__global__ __launch_bounds__(256) void lstm_rec(
    const float* __restrict__ gx,   // [1280, 2048]
    bf16* __restrict__ seq,         // [B,T,E]
    const float* __restrict__ feats,
    const bf16* __restrict__ Whh,   // [2048,512] bf16
    unsigned int* __restrict__ bar)
{
  const long XS = (long)Tt * Ee;
  __shared__ __align__(16) bf16 wl[4][64][16][8];   // 64 KB W_hh slice
  __shared__ float gsm[4][64][17];                  // 17.4 KB, padded

  int tid = threadIdx.x;
  int g = tid >> 6;                 // wave id == gate id (0=i,1=f,2=g,3=o)
  int lane = tid & 63;
  int quad = lane >> 4, ln = lane & 15;
  int j0 = blockIdx.x * 16;
  int bid = blockIdx.x;

  // stage W_hh slice (once)
#pragma unroll
  for (int q = 0; q < 16; ++q) {
    int c = q * 256 + tid;
    int row = c >> 6, k8 = c & 63;
    int gg = row >> 4, rr = row & 15;
    *(uint4*)&wl[gg][k8][rr][0] =
        *(const uint4*)(Whh + ((size_t)gg * Ee + j0 + rr) * Ee + k8 * 8);
  }

  // pointwise ownership: thread -> (b = tid>>2, 4 consecutive j at jq)
  int bq = tid >> 2;                // 0..63
  int jq = (tid & 3) * 4;           // 0,4,8,12
  const float* gxb = gx + (size_t)bq * Tt * (4 * Ee) + j0 + jq;

  // cell state (float4-wise) : c0 = features
  f32x4 creg = *(const f32x4*)(feats + (size_t)bq * Ee + j0 + jq);

  // prefetch gx for step t=1 into registers (one float4 per gate)
  f32x4 pre[4];
#pragma unroll
  for (int gg = 0; gg < 4; ++gg) pre[gg] = *(const f32x4*)(gxb + gg * Ee);
  __syncthreads();

  for (int t = 1; t < Tt; ++t) {
    if (t > 1) {
      bf16* hb = seq + (size_t)(t - 1) * Ee;   // h_{t-1}
      f32x4 zero = {0.f, 0.f, 0.f, 0.f};
      f32x4 acc[4];
#pragma unroll
      for (int mt = 0; mt < 4; ++mt) acc[mt] = zero;
#pragma unroll 4
      for (int kk = 0; kk < 16; ++kk) {
        int k = kk * 32 + quad * 8;
        bf16x8 bfrag = *(const bf16x8*)&wl[g][kk * 4 + quad][ln][0];
#pragma unroll
        for (int mt = 0; mt < 4; ++mt) {
          // coherent 8B atomic loads (sc0 sc1): read h fresh from IC,
          // no L2 invalidate needed anywhere.
          union { unsigned long long q[2]; bf16x8 v; } hl;
          unsigned long long* hp =
              (unsigned long long*)(hb + (size_t)(mt * 16 + ln) * XS + k);
          hl.q[0] = __hip_atomic_load(hp, __ATOMIC_RELAXED, __HIP_MEMORY_SCOPE_AGENT);
          hl.q[1] = __hip_atomic_load(hp + 1, __ATOMIC_RELAXED, __HIP_MEMORY_SCOPE_AGENT);
          acc[mt] = __builtin_amdgcn_mfma_f32_16x16x32_bf16(hl.v, bfrag, acc[mt], 0, 0, 0);
        }
      }
#pragma unroll
      for (int mt = 0; mt < 4; ++mt)
#pragma unroll
        for (int r = 0; r < 4; ++r)
          gsm[g][mt * 16 + quad * 4 + r][ln] = acc[mt][r];
    }
    __syncthreads();

    // pointwise: 4 consecutive j of one b per thread; gx already in regs
    union { ushort4 u; unsigned long long q; bf16 h[4]; } st;
#pragma unroll
    for (int jj = 0; jj < 4; ++jj) {
      int jl = jq + jj;
      float iv = pre[0][jj];
      float fv = pre[1][jj];
      float gv = pre[2][jj];
      float ov = pre[3][jj];
      if (t > 1) {
        iv += gsm[0][bq][jl];
        fv += gsm[1][bq][jl];
        gv += gsm[2][bq][jl];
        ov += gsm[3][bq][jl];
      }
      iv = 1.f / (1.f + __expf(-iv));
      fv = 1.f / (1.f + __expf(-fv));
      ov = 1.f / (1.f + __expf(-ov));
      gv = tanhf(gv);
      creg[jj] = fv * creg[jj] + iv * gv;
      st.h[jj] = f2bf(ov * tanhf(creg[jj]));
    }
    // coherent 8B atomic store (sc0 sc1): h goes straight to IC.
    __hip_atomic_store(
        (unsigned long long*)(seq + (size_t)bq * XS + (size_t)t * Ee + j0 + jq),
        st.q, __ATOMIC_RELAXED, __HIP_MEMORY_SCOPE_AGENT);

    if (t < Tt - 1) {
      // prefetch gx for step t+1 (normal cached loads; L2 stays warm)
#pragma unroll
      for (int gg = 0; gg < 4; ++gg)
        pre[gg] = *(const f32x4*)(gxb + (size_t)t * (4 * Ee) + gg * Ee);

      // ---- pure-relaxed all-to-all flag barrier (no fences/cache ops) ----
      __syncthreads();   // drains all waves' h atomic stores (vmcnt 0)
      if (tid == 0)
        __hip_atomic_store(&bar[bid * 16], (unsigned)t, __ATOMIC_RELAXED,
                           __HIP_MEMORY_SCOPE_AGENT);
      if (tid < NB) {
        while (__hip_atomic_load(&bar[tid * 16], __ATOMIC_RELAXED,
                                 __HIP_MEMORY_SCOPE_AGENT) < (unsigned)t)
          __builtin_amdgcn_s_sleep(1);
      }
      __syncthreads();
    }
  }
}

// ---------------------------------------------------------------------------
// Kernel 4: logits = seq[1280,512](bf16) @ W_out[32000,512](fp32)^T + b_out.
// R0 proven skeleton (128x128 tile, BK=64, 32 KB LDS, 2500 tiles) with an
// XCD-aware swizzle: all 10 M-tiles of an N-band get bids congruent mod 8,
// so one band's W panel is fetched into exactly ONE XCD's L2 (10x reuse).
// grid = 2560 blocks (60 no-op), 256 threads.
// ---------------------------------------------------------------------------
#define BM 128
#define BN 128
#define BK 64

__global__ __launch_bounds__(256) void out_gemm(const bf16* __restrict__ A,    // [1280,512] bf16
                                                const float* __restrict__ Bw,  // [32000,512] fp32
                                                const float* __restrict__ bias,
                                                float* __restrict__ Cb) {
  __shared__ __align__(16) bf16 As[BM * BK];   // 16 KB
  __shared__ __align__(16) bf16 Bs[BN * BK];   // 16 KB
  int bid = blockIdx.x;
  int xcd = bid & 7, slot = bid >> 3;          // slot 0..319
  int mi = slot % 10, grp = slot / 10;         // grp 0..31
  int band = grp * 8 + xcd;                    // N-band 0..255
  if (band >= Vv / BN) return;
  int m0 = mi * BM, n0 = band * BN;

  int tid = threadIdx.x;
  int lane = tid & 63;
  int quad = lane >> 4, ln = lane & 15;
  int wid = tid >> 6;
  int wm = wid & 1, wn = wid >> 1;

  f32x4 zero = {0.f, 0.f, 0.f, 0.f};
  f32x4 acc[4][4];
#pragma unroll
  for (int mt = 0; mt < 4; ++mt)
#pragma unroll
    for (int nt = 0; nt < 4; ++nt) acc[mt][nt] = zero;

  for (int k0 = 0; k0 < Ee; k0 += BK) {
    uint4 avv[4];
    float4 bf0[4], bf1[4];
#pragma unroll
    for (int q = 0; q < 4; ++q) {
      int fb = (q * 256 + tid) * 16;   // byte offset within bf16 tile
      int row = fb >> 7;               // 128 B per row (64 bf16)
      int c8 = (fb & 127) >> 1;        // bf16 column start
      avv[q] = *(const uint4*)((const char*)A + ((size_t)(m0 + row) * Ee + k0) * 2 + (fb & 127));
      const float* src = Bw + (size_t)(n0 + row) * Ee + k0 + c8;
      bf0[q] = *(const float4*)(src);
      bf1[q] = *(const float4*)(src + 4);
    }
#pragma unroll
    for (int q = 0; q < 4; ++q) {
      int fb = (q * 256 + tid) * 16;
      *(uint4*)((char*)As + fb) = avv[q];
      union { uint4 u; bf16 h[8]; } pk;
      pk.h[0] = f2bf(bf0[q].x); pk.h[1] = f2bf(bf0[q].y);
      pk.h[2] = f2bf(bf0[q].z); pk.h[3] = f2bf(bf0[q].w);
      pk.h[4] = f2bf(bf1[q].x); pk.h[5] = f2bf(bf1[q].y);
      pk.h[6] = f2bf(bf1[q].z); pk.h[7] = f2bf(bf1[q].w);
      *(uint4*)((char*)Bs + fb) = pk.u;
    }
    __syncthreads();

#pragma unroll
    for (int kk = 0; kk < 2; ++kk) {
      int kb = (kk * 32 + quad * 8) * 2;
      bf16x8 af[4], bfv[4];
#pragma unroll
      for (int mt = 0; mt < 4; ++mt)
        af[mt] = *(const bf16x8*)((const char*)As + (wm * 64 + mt * 16 + ln) * 128 + kb);
#pragma unroll
      for (int nt = 0; nt < 4; ++nt)
        bfv[nt] = *(const bf16x8*)((const char*)Bs + (wn * 64 + nt * 16 + ln) * 128 + kb);
#pragma unroll
      for (int mt = 0; mt < 4; ++mt)
#pragma unroll
        for (int nt = 0; nt < 4; ++nt)
          acc[mt][nt] = __builtin_amdgcn_mfma_f32_16x16x32_bf16(af[mt], bfv[nt], acc[mt][nt], 0, 0, 0);
    }
    __syncthreads();
  }

  // epilogue: + bias, fp32 store. D: col = lane&15, row = quad*4 + reg.
  float bv[4];
#pragma unroll
  for (int nt = 0; nt < 4; ++nt)
    bv[nt] = bias[n0 + wn * 64 + nt * 16 + ln];
#pragma unroll
  for (int mt = 0; mt < 4; ++mt) {
#pragma unroll
    for (int nt = 0; nt < 4; ++nt) {
      int col = n0 + wn * 64 + nt * 16 + ln;
#pragma unroll
      for (int r = 0; r < 4; ++r) {
        int row = m0 + wm * 64 + mt * 16 + quad * 4 + r;
        Cb[(size_t)row * Vv + col] = acc[mt][nt][r] + bv[nt];
      }
    }
  }
}

// ---------------------------------------------------------------------------
extern "C" void kernel_launch(void* const* d_in, const int* in_sizes, int n_in,
                              void* d_out, int out_size, void* d_ws, size_t ws_size,
                              hipStream_t stream) {
  (void)in_sizes; (void)n_in; (void)out_size; (void)ws_size;
  const float* feats = (const float*)d_in[0];
  const int*   caps  = (const int*)d_in[1];
  const float* Wemb  = (const float*)d_in[2];
  const float* Wout  = (const float*)d_in[3];
  const float* bout  = (const float*)d_in[4];
  const float* Wih   = (const float*)d_in[5];
  const float* Whh   = (const float*)d_in[6];
  const float* bih   = (const float*)d_in[7];
  const float* bhh   = (const float*)d_in[8];
  float* out = (float*)d_out;

  // workspace layout (16B-aligned), ~17.3 MB total:
  bf16* emb    = (bf16*)d_ws;                          // [B,T,E]     1.31 MB
  bf16* seq    = emb   + (size_t)Bb * Tt * Ee;         // [B,T,E]     1.31 MB
  bf16* Wih_b  = seq   + (size_t)Bb * Tt * Ee;         // [4E,E]      2 MB
  bf16* Whh_b  = Wih_b + (size_t)4 * Ee * Ee;          // [4E,E]      2 MB
  float* gx    = (float*)(Whh_b + (size_t)4 * Ee * Ee);// [B*T,4E]    10.5 MB
  unsigned int* bar = (unsigned int*)(gx + (size_t)Bb * Tt * 4 * Ee); // 2.2 KB

  const int WN4 = (4 * Ee * Ee) / 4;                   // float4s per weight matrix
  convert_w<<<WN4 / 256, 256, 0, stream>>>(Wih, Wih_b);
  convert_w<<<WN4 / 256, 256, 0, stream>>>(Whh, Whh_b);
  embed_init<<<Bb * Tt, 128, 0, stream>>>(caps, Wemb, emb, seq, bar);
  xproj<<<dim3(16, 10), 256, 0, stream>>>(emb, Wih_b, bih, bhh, gx);
  lstm_rec<<<NB, 256, 0, stream>>>(gx, seq, feats, Whh_b, bar);
  out_gemm<<<2560, 256, 0, stream>>>(seq, Wout, bout, out);
}

// Round 6
// 520.479 us; speedup vs baseline: 1.2955x; 1.2955x over previous
//
#include <hip/hip_runtime.h>
#include <hip/hip_bf16.h>

#define Bb 64
#define Tt 20
#define Ee 512
#define Vv 32000
#define NB 32            // blocks in recurrent kernel

typedef __hip_bfloat16 bf16;
typedef __attribute__((ext_vector_type(8))) short bf16x8;
typedef __attribute__((ext_vector_type(4))) float f32x4;

__device__ __forceinline__ bf16 f2bf(float x) { return __float2bfloat16(x); }

// ---------------------------------------------------------------------------
// Kernel 1: embedding gather (fp32 -> bf16) + barrier-flag reset.
//  bar layout: arrive flags at bar[b*16] (64B stride, b<NB).
// ---------------------------------------------------------------------------
__global__ void embed_init(const int* __restrict__ caps, const float* __restrict__ Wemb,
                           bf16* __restrict__ emb, bf16* __restrict__ seq,
                           unsigned int* __restrict__ bar) {
  int row = blockIdx.x;            // b*T + t
  int t = row % Tt;
  int tid = threadIdx.x;           // 0..127
  if (row == 0) {
    for (int i = tid; i < NB * 16 + Tt; i += 128) bar[i] = 0;
  }
  int tok = caps[row];
  float4 v = ((const float4*)(Wemb + (size_t)tok * Ee))[tid];
  union { ushort4 u; bf16 h[4]; } pk;
  pk.h[0] = f2bf(v.x); pk.h[1] = f2bf(v.y); pk.h[2] = f2bf(v.z); pk.h[3] = f2bf(v.w);
  ((ushort4*)(emb + (size_t)row * Ee))[tid] = pk.u;
  if (t == 0) ((ushort4*)(seq + (size_t)row * Ee))[tid] = pk.u;   // row == b*T
}

// ---------------------------------------------------------------------------
// Kernel 2: x-projection (R0 GEMM skeleton, 32 KB LDS, multi-block/CU):
//   gx[row, col] = emb[row,:] @ W_ih[col,:] + bih[col] + bhh[col]
// W_ih read as fp32, converted during LDS staging (convert_w eliminated).
// grid = (16 n-tiles, 10 m-tiles), 256 threads, 128x128 tile, BK=64.
// ---------------------------------------------------------------------------
__global__ __launch_bounds__(256) void xproj(
    const bf16* __restrict__ A,     // emb [1280,512] bf16
    const float* __restrict__ Bw,   // W_ih [2048,512] fp32
    const float* __restrict__ bih, const float* __restrict__ bhh,
    float* __restrict__ gx)         // [1280,2048] fp32
{
  __shared__ __align__(16) bf16 As[128 * 64];   // 16 KB
  __shared__ __align__(16) bf16 Bs[128 * 64];   // 16 KB
  int tid = threadIdx.x;
  int lane = tid & 63;
  int quad = lane >> 4, ln = lane & 15;
  int wid = tid >> 6;
  int wm = wid & 1, wn = wid >> 1;
  int n0 = blockIdx.x * 128, m0 = blockIdx.y * 128;

  f32x4 zero = {0.f, 0.f, 0.f, 0.f};
  f32x4 acc[4][4];
#pragma unroll
  for (int mt = 0; mt < 4; ++mt)
#pragma unroll
    for (int nt = 0; nt < 4; ++nt) acc[mt][nt] = zero;

  for (int k0 = 0; k0 < Ee; k0 += 64) {
    uint4 avv[4];
    float4 bf0[4], bf1[4];
#pragma unroll
    for (int q = 0; q < 4; ++q) {
      int fb = (q * 256 + tid) * 16;   // byte offset within bf16 tile
      int row = fb >> 7;               // 128 B per row (64 bf16)
      int c8 = (fb & 127) >> 1;        // bf16 column start
      avv[q] = *(const uint4*)((const char*)A + ((size_t)(m0 + row) * Ee + k0) * 2 + (fb & 127));
      const float* src = Bw + (size_t)(n0 + row) * Ee + k0 + c8;
      bf0[q] = *(const float4*)(src);
      bf1[q] = *(const float4*)(src + 4);
    }
#pragma unroll
    for (int q = 0; q < 4; ++q) {
      int fb = (q * 256 + tid) * 16;
      *(uint4*)((char*)As + fb) = avv[q];
      union { uint4 u; bf16 h[8]; } pk;
      pk.h[0] = f2bf(bf0[q].x); pk.h[1] = f2bf(bf0[q].y);
      pk.h[2] = f2bf(bf0[q].z); pk.h[3] = f2bf(bf0[q].w);
      pk.h[4] = f2bf(bf1[q].x); pk.h[5] = f2bf(bf1[q].y);
      pk.h[6] = f2bf(bf1[q].z); pk.h[7] = f2bf(bf1[q].w);
      *(uint4*)((char*)Bs + fb) = pk.u;
    }
    __syncthreads();

#pragma unroll
    for (int kk = 0; kk < 2; ++kk) {
      int kb = (kk * 32 + quad * 8) * 2;
      bf16x8 af[4], bfv[4];
#pragma unroll
      for (int mt = 0; mt < 4; ++mt)
        af[mt] = *(const bf16x8*)((const char*)As + (wm * 64 + mt * 16 + ln) * 128 + kb);
#pragma unroll
      for (int nt = 0; nt < 4; ++nt)
        bfv[nt] = *(const bf16x8*)((const char*)Bs + (wn * 64 + nt * 16 + ln) * 128 + kb);
#pragma unroll
      for (int mt = 0; mt < 4; ++mt)
#pragma unroll
        for (int nt = 0; nt < 4; ++nt)
          acc[mt][nt] = __builtin_amdgcn_mfma_f32_16x16x32_bf16(af[mt], bfv[nt], acc[mt][nt], 0, 0, 0);
    }
    __syncthreads();
  }

#pragma unroll
  for (int nt = 0; nt < 4; ++nt) {
    int col = n0 + wn * 64 + nt * 16 + ln;
    float bsum = bih[col] + bhh[col];
#pragma unroll
    for (int mt = 0; mt < 4; ++mt) {
#pragma unroll
      for (int r = 0; r < 4; ++r) {
        int row = m0 + wm * 64 + mt * 16 + quad * 4 + r;
        gx[(size_t)row * (4 * Ee) + col] = acc[mt][nt][r] + bsum;
      }
    }
  }
}

// ---------------------------------------------------------------------------
// Kernel 3: recurrent part, ALL 19 steps, 32 blocks x 256 threads.
//  ZERO cache-maintenance: h is exchanged via a block-exclusive staging
//  buffer hbuf[t][blk][64][16] (2 KB line-exclusive region per block/step).
//   - producers: ONE relaxed 8B agent-atomic store per thread (write-through
//     to IC; region is line-exclusive so no false sharing, and the block
//     overwrites its whole region so L2-allocate races are benign).
//   - consumers: NORMAL cached 16B vector loads (each address read once per
//     launch -> no stale-line hazard; cross-launch handled by AQL acquire).
//   - barrier: pure relaxed flags (no release/acquire/fence) -> L2 is never
//     invalidated, so gx and W_hh stay L2-warm across all 19 steps.
//  W_hh staged fp32->bf16 into LDS once. gx pre-folded with biases; c in
//  regs; gx for next step prefetched into registers before the barrier.
//  h also stored (normal) to seq for out_gemm.
// ---------------------------------------------------------------------------
__global__ __launch_bounds__(256) void lstm_rec(
    const float* __restrict__ gx,   // [1280, 2048]
    bf16* __restrict__ seq,         // [B,T,E]
    bf16* __restrict__ hbuf,        // [T][NB][64][16]
    const float* __restrict__ feats,
    const float* __restrict__ Whh,  // [2048,512] fp32
    unsigned int* __restrict__ bar)
{
  const long XS = (long)Tt * Ee;
  __shared__ __align__(16) bf16 wl[4][64][16][8];   // 64 KB W_hh slice
  __shared__ float gsm[4][64][17];                  // 17.4 KB, padded

  int tid = threadIdx.x;
  int g = tid >> 6;                 // wave id == gate id (0=i,1=f,2=g,3=o)
  int lane = tid & 63;
  int quad = lane >> 4, ln = lane & 15;
  int j0 = blockIdx.x * 16;
  int bid = blockIdx.x;

  // stage W_hh slice fp32 -> bf16 (once)
#pragma unroll
  for (int q = 0; q < 16; ++q) {
    int c = q * 256 + tid;
    int row = c >> 6, k8 = c & 63;
    int gg = row >> 4, rr = row & 15;
    const float* src = Whh + ((size_t)gg * Ee + j0 + rr) * Ee + k8 * 8;
    float4 f0 = *(const float4*)src;
    float4 f1 = *(const float4*)(src + 4);
    union { uint4 u; bf16 h[8]; } pk;
    pk.h[0] = f2bf(f0.x); pk.h[1] = f2bf(f0.y); pk.h[2] = f2bf(f0.z); pk.h[3] = f2bf(f0.w);
    pk.h[4] = f2bf(f1.x); pk.h[5] = f2bf(f1.y); pk.h[6] = f2bf(f1.z); pk.h[7] = f2bf(f1.w);
    *(uint4*)&wl[gg][k8][rr][0] = pk.u;
  }

  // pointwise ownership: thread -> (b = tid>>2, 4 consecutive j at jq)
  int bq = tid >> 2;                // 0..63
  int jq = (tid & 3) * 4;           // 0,4,8,12
  const float* gxb = gx + (size_t)bq * Tt * (4 * Ee) + j0 + jq;

  // cell state (float4-wise) : c0 = features
  f32x4 creg = *(const f32x4*)(feats + (size_t)bq * Ee + j0 + jq);

  // prefetch gx for step t=1 into registers (one float4 per gate)
  f32x4 pre[4];
#pragma unroll
  for (int gg = 0; gg < 4; ++gg) pre[gg] = *(const f32x4*)(gxb + gg * Ee);
  __syncthreads();

  for (int t = 1; t < Tt; ++t) {
    if (t > 1) {
      // h_{t-1}: hbuf regions [(t-1)*NB + kb][64][16], kb = k>>4
      const bf16* hbase = hbuf + (size_t)(t - 1) * NB * 1024;
      f32x4 zero = {0.f, 0.f, 0.f, 0.f};
      f32x4 acc[4];
#pragma unroll
      for (int mt = 0; mt < 4; ++mt) acc[mt] = zero;
#pragma unroll 4
      for (int kk = 0; kk < 16; ++kk) {
        int k = kk * 32 + quad * 8;
        int kb = k >> 4, ko = k & 15;
        bf16x8 bfrag = *(const bf16x8*)&wl[g][kk * 4 + quad][ln][0];
#pragma unroll
        for (int mt = 0; mt < 4; ++mt) {
          bf16x8 afrag = *(const bf16x8*)(hbase + (size_t)kb * 1024 +
                                          (mt * 16 + ln) * 16 + ko);
          acc[mt] = __builtin_amdgcn_mfma_f32_16x16x32_bf16(afrag, bfrag, acc[mt], 0, 0, 0);
        }
      }
#pragma unroll
      for (int mt = 0; mt < 4; ++mt)
#pragma unroll
        for (int r = 0; r < 4; ++r)
          gsm[g][mt * 16 + quad * 4 + r][ln] = acc[mt][r];
    }
    __syncthreads();

    // pointwise: 4 consecutive j of one b per thread; gx already in regs
    union { ushort4 u; unsigned long long q; bf16 h[4]; } st;
#pragma unroll
    for (int jj = 0; jj < 4; ++jj) {
      int jl = jq + jj;
      float iv = pre[0][jj];
      float fv = pre[1][jj];
      float gv = pre[2][jj];
      float ov = pre[3][jj];
      if (t > 1) {
        iv += gsm[0][bq][jl];
        fv += gsm[1][bq][jl];
        gv += gsm[2][bq][jl];
        ov += gsm[3][bq][jl];
      }
      iv = 1.f / (1.f + __expf(-iv));
      fv = 1.f / (1.f + __expf(-fv));
      ov = 1.f / (1.f + __expf(-ov));
      gv = tanhf(gv);
      creg[jj] = fv * creg[jj] + iv * gv;
      st.h[jj] = f2bf(ov * tanhf(creg[jj]));
    }
    // h -> block-exclusive hbuf region (write-through 8B atomic, IC-visible)
    __hip_atomic_store(
        (unsigned long long*)(hbuf + ((size_t)t * NB + bid) * 1024 + bq * 16 + jq),
        st.q, __ATOMIC_RELAXED, __HIP_MEMORY_SCOPE_AGENT);
    // h -> seq (normal store; consumed by out_gemm after kernel boundary)
    *(ushort4*)(seq + (size_t)bq * XS + (size_t)t * Ee + j0 + jq) = st.u;

    if (t < Tt - 1) {
      // prefetch gx for step t+1 (normal cached loads; L2 stays warm)
#pragma unroll
      for (int gg = 0; gg < 4; ++gg)
        pre[gg] = *(const f32x4*)(gxb + (size_t)t * (4 * Ee) + gg * Ee);

      // ---- pure-relaxed all-to-all flag barrier (no fences/cache ops) ----
      __syncthreads();   // drains all waves' hbuf atomic stores (vmcnt 0)
      if (tid == 0)
        __hip_atomic_store(&bar[bid * 16], (unsigned)t, __ATOMIC_RELAXED,
                           __HIP_MEMORY_SCOPE_AGENT);
      if (tid < NB) {
        while (__hip_atomic_load(&bar[tid * 16], __ATOMIC_RELAXED,
                                 __HIP_MEMORY_SCOPE_AGENT) < (unsigned)t)
          __builtin_amdgcn_s_sleep(1);
      }
      __syncthreads();
    }
  }
}

// ---------------------------------------------------------------------------
// Kernel 4: logits = seq[1280,512](bf16) @ W_out[32000,512](fp32)^T + b_out.
// R0 skeleton (128x128 tile, BK=64, 32 KB LDS) + XCD swizzle: the 10 M-tiles
// of one N-band get bids congruent mod 8 -> one XCD's L2 holds the W panel.
// grid = 2560 blocks (60 no-op), 256 threads.
// ---------------------------------------------------------------------------
#define BM 128
#define BN 128
#define BK 64

__global__ __launch_bounds__(256) void out_gemm(const bf16* __restrict__ A,    // [1280,512] bf16
                                                const float* __restrict__ Bw,  // [32000,512] fp32
                                                const float* __restrict__ bias,
                                                float* __restrict__ Cb) {
  __shared__ __align__(16) bf16 As[BM * BK];   // 16 KB
  __shared__ __align__(16) bf16 Bs[BN * BK];   // 16 KB
  int bid = blockIdx.x;
  int xcd = bid & 7, slot = bid >> 3;          // slot 0..319
  int mi = slot % 10, grp = slot / 10;         // grp 0..31
  int band = grp * 8 + xcd;                    // N-band 0..255
  if (band >= Vv / BN) return;
  int m0 = mi * BM, n0 = band * BN;

  int tid = threadIdx.x;
  int lane = tid & 63;
  int quad = lane >> 4, ln = lane & 15;
  int wid = tid >> 6;
  int wm = wid & 1, wn = wid >> 1;

  f32x4 zero = {0.f, 0.f, 0.f, 0.f};
  f32x4 acc[4][4];
#pragma unroll
  for (int mt = 0; mt < 4; ++mt)
#pragma unroll
    for (int nt = 0; nt < 4; ++nt) acc[mt][nt] = zero;

  for (int k0 = 0; k0 < Ee; k0 += BK) {
    uint4 avv[4];
    float4 bf0[4], bf1[4];
#pragma unroll
    for (int q = 0; q < 4; ++q) {
      int fb = (q * 256 + tid) * 16;   // byte offset within bf16 tile
      int row = fb >> 7;               // 128 B per row (64 bf16)
      int c8 = (fb & 127) >> 1;        // bf16 column start
      avv[q] = *(const uint4*)((const char*)A + ((size_t)(m0 + row) * Ee + k0) * 2 + (fb & 127));
      const float* src = Bw + (size_t)(n0 + row) * Ee + k0 + c8;
      bf0[q] = *(const float4*)(src);
      bf1[q] = *(const float4*)(src + 4);
    }
#pragma unroll
    for (int q = 0; q < 4; ++q) {
      int fb = (q * 256 + tid) * 16;
      *(uint4*)((char*)As + fb) = avv[q];
      union { uint4 u; bf16 h[8]; } pk;
      pk.h[0] = f2bf(bf0[q].x); pk.h[1] = f2bf(bf0[q].y);
      pk.h[2] = f2bf(bf0[q].z); pk.h[3] = f2bf(bf0[q].w);
      pk.h[4] = f2bf(bf1[q].x); pk.h[5] = f2bf(bf1[q].y);
      pk.h[6] = f2bf(bf1[q].z); pk.h[7] = f2bf(bf1[q].w);
      *(uint4*)((char*)Bs + fb) = pk.u;
    }
    __syncthreads();

#pragma unroll
    for (int kk = 0; kk < 2; ++kk) {
      int kb = (kk * 32 + quad * 8) * 2;
      bf16x8 af[4], bfv[4];
#pragma unroll
      for (int mt = 0; mt < 4; ++mt)
        af[mt] = *(const bf16x8*)((const char*)As + (wm * 64 + mt * 16 + ln) * 128 + kb);
#pragma unroll
      for (int nt = 0; nt < 4; ++nt)
        bfv[nt] = *(const bf16x8*)((const char*)Bs + (wn * 64 + nt * 16 + ln) * 128 + kb);
#pragma unroll
      for (int mt = 0; mt < 4; ++mt)
#pragma unroll
        for (int nt = 0; nt < 4; ++nt)
          acc[mt][nt] = __builtin_amdgcn_mfma_f32_16x16x32_bf16(af[mt], bfv[nt], acc[mt][nt], 0, 0, 0);
    }
    __syncthreads();
  }

  // epilogue: + bias, fp32 store. D: col = lane&15, row = quad*4 + reg.
  float bv[4];
#pragma unroll
  for (int nt = 0; nt < 4; ++nt)
    bv[nt] = bias[n0 + wn * 64 + nt * 16 + ln];
#pragma unroll
  for (int mt = 0; mt < 4; ++mt) {
#pragma unroll
    for (int nt = 0; nt < 4; ++nt) {
      int col = n0 + wn * 64 + nt * 16 + ln;
#pragma unroll
      for (int r = 0; r < 4; ++r) {
        int row = m0 + wm * 64 + mt * 16 + quad * 4 + r;
        Cb[(size_t)row * Vv + col] = acc[mt][nt][r] + bv[nt];
      }
    }
  }
}

// ---------------------------------------------------------------------------
extern "C" void kernel_launch(void* const* d_in, const int* in_sizes, int n_in,
                              void* d_out, int out_size, void* d_ws, size_t ws_size,
                              hipStream_t stream) {
  (void)in_sizes; (void)n_in; (void)out_size; (void)ws_size;
  const float* feats = (const float*)d_in[0];
  const int*   caps  = (const int*)d_in[1];
  const float* Wemb  = (const float*)d_in[2];
  const float* Wout  = (const float*)d_in[3];
  const float* bout  = (const float*)d_in[4];
  const float* Wih   = (const float*)d_in[5];
  const float* Whh   = (const float*)d_in[6];
  const float* bih   = (const float*)d_in[7];
  const float* bhh   = (const float*)d_in[8];
  float* out = (float*)d_out;

  // workspace layout (16B-aligned), ~14.7 MB total:
  bf16* emb    = (bf16*)d_ws;                          // [B,T,E]       1.31 MB
  bf16* seq    = emb   + (size_t)Bb * Tt * Ee;         // [B,T,E]       1.31 MB
  bf16* hbuf   = seq   + (size_t)Bb * Tt * Ee;         // [T][NB][64][16] 1.31 MB
  float* gx    = (float*)(hbuf + (size_t)Tt * NB * 1024); // [B*T,4E]   10.5 MB
  unsigned int* bar = (unsigned int*)(gx + (size_t)Bb * Tt * 4 * Ee);  // 2.2 KB

  embed_init<<<Bb * Tt, 128, 0, stream>>>(caps, Wemb, emb, seq, bar);
  xproj<<<dim3(16, 10), 256, 0, stream>>>(emb, Wih, bih, bhh, gx);
  lstm_rec<<<NB, 256, 0, stream>>>(gx, seq, hbuf, feats, Whh, bar);
  out_gemm<<<2560, 256, 0, stream>>>(seq, Wout, bout, out);
}